// Round 3
// baseline (1827.154 us; speedup 1.0000x reference)
//
#include <hip/hip_runtime.h>

// HeteroGAT on MI355X. Round 3: runtime dtype probe (fp32 vs bf16 inputs),
// canonicalize all float inputs to bf16 in ws, run the verified bf16 MFMA
// pipeline, store final output in the detected dtype.
// msg kernels: flag==nullptr -> internal bf16 store at element n*256+cb.
// flag!=nullptr (final layer): store to d_out in detected dtype; author kernel
// applies the NP*256-element block offset itself.

#define NP 100000
#define NA 50000
#define NE 250000

typedef __attribute__((ext_vector_type(8))) short short8;
typedef __attribute__((ext_vector_type(4))) float f32x4;

__device__ __forceinline__ float b2f(unsigned short u) {
  union { unsigned int i; float f; } v; v.i = ((unsigned int)u) << 16; return v.f;
}
__device__ __forceinline__ unsigned short f2b(float f) {
  union { float f; unsigned int i; } v; v.f = f;
  unsigned int u = v.i;
  return (unsigned short)((u + 0x7fffu + ((u >> 16) & 1u)) >> 16);
}

__global__ void probe_kernel(const unsigned short* __restrict__ x, int* __restrict__ flag)
{
  __shared__ int cnt;
  if (threadIdx.x == 0) cnt = 0;
  __syncthreads();
  int c = 0;
  for (int i = threadIdx.x; i < 4096; i += 256) {
    unsigned int e = (x[i] >> 7) & 0xFFu;
    if (e >= 0xC0u) c++;
  }
  atomicAdd(&cnt, c);
  __syncthreads();
  if (threadIdx.x == 0) *flag = (cnt > 64) ? 1 : 0;   // 1 = inputs are fp32
}

__global__ void conv_kernel(const unsigned short* __restrict__ src,
                            unsigned short* __restrict__ dst, int n,
                            const int* __restrict__ flag)
{
  int i = blockIdx.x * 256 + threadIdx.x;
  if (i >= n) return;
  if (*flag) {
    const float* f = (const float*)src;
    dst[i] = f2b(f[i]);
  } else {
    dst[i] = src[i];
  }
}

template <int RELU>
__global__ __launch_bounds__(256) void gemm256(
    const unsigned short* __restrict__ A, const unsigned short* __restrict__ BT,
    unsigned short* __restrict__ C, int M, int K, const unsigned short* __restrict__ bias)
{
  __shared__ __align__(16) unsigned short As[128 * 64];
  __shared__ __align__(16) unsigned short Bs[128 * 64];
  const int t = threadIdx.x;
  const int lane = t & 63;
  const int w = t >> 6;
  const int wr = w >> 1, wc = w & 1;
  const int quad = lane >> 4;
  const int l16 = lane & 15;
  const int m0 = blockIdx.x * 128;
  const int n0 = blockIdx.y * 128;

  f32x4 acc[4][4];
#pragma unroll
  for (int i = 0; i < 4; i++)
#pragma unroll
    for (int j = 0; j < 4; j++) { acc[i][j][0] = 0.f; acc[i][j][1] = 0.f; acc[i][j][2] = 0.f; acc[i][j][3] = 0.f; }

  const int nkc = K >> 6;
  for (int kc = 0; kc < nkc; ++kc) {
    uint4 av[4], bv[4];
#pragma unroll
    for (int i = 0; i < 4; i++) {
      int chunk = i * 256 + t;
      int r = chunk >> 3, c8 = chunk & 7;
      int gr = m0 + r; gr = gr < M ? gr : (M - 1);
      av[i] = *(const uint4*)(A + (size_t)gr * K + (kc * 64 + c8 * 8));
      bv[i] = *(const uint4*)(BT + (size_t)(n0 + r) * K + (kc * 64 + c8 * 8));
    }
    __syncthreads();
#pragma unroll
    for (int i = 0; i < 4; i++) {
      int chunk = i * 256 + t;
      *(uint4*)(As + chunk * 8) = av[i];
      *(uint4*)(Bs + chunk * 8) = bv[i];
    }
    __syncthreads();
#pragma unroll
    for (int ks = 0; ks < 2; ++ks) {
      short8 af[4], bq[4];
#pragma unroll
      for (int i = 0; i < 4; i++)
        af[i] = *(const short8*)(As + (wr * 64 + i * 16 + l16) * 64 + ks * 32 + quad * 8);
#pragma unroll
      for (int j = 0; j < 4; j++)
        bq[j] = *(const short8*)(Bs + (wc * 64 + j * 16 + l16) * 64 + ks * 32 + quad * 8);
#pragma unroll
      for (int i = 0; i < 4; i++)
#pragma unroll
        for (int j = 0; j < 4; j++)
          acc[i][j] = __builtin_amdgcn_mfma_f32_16x16x32_bf16(af[i], bq[j], acc[i][j], 0, 0, 0);
    }
  }
#pragma unroll
  for (int j = 0; j < 4; j++) {
    int col = n0 + wc * 64 + j * 16 + l16;
    float bv2 = bias ? b2f(bias[col]) : 0.f;
#pragma unroll
    for (int i = 0; i < 4; i++) {
      int rbase = m0 + wr * 64 + i * 16 + quad * 4;
#pragma unroll
      for (int r = 0; r < 4; r++) {
        int row = rbase + r;
        if (row < M) {
          float v = acc[i][j][r] + bv2;
          if (RELU) v = v > 0.f ? v : 0.f;
          C[(size_t)row * 256 + col] = f2b(v);
        }
      }
    }
  }
}

// Wp cols: 0-3 al_s(t=1), 4-7 al_s(t=2), 8-11 al_d(t=0), 12-15 al_d(t=1)
// Wa cols: 0-3 al_s(t=0), 4-7 al_d(t=2)
__global__ void fold_kernel(const unsigned short* __restrict__ lin_src,
                            const unsigned short* __restrict__ lin_dst,
                            const unsigned short* __restrict__ att_src,
                            const unsigned short* __restrict__ att_dst,
                            float* __restrict__ Wp, float* __restrict__ Wa)
{
  int idx = blockIdx.x * 256 + threadIdx.x;
  if (idx >= 12288) return;
  const unsigned short *L, *At;
  int l, k, j, t, h;
  if (idx < 8192) {
    l = idx >> 12; int rem = idx & 4095; k = rem >> 4; j = rem & 15;
    if (j < 4)       { t = 1; h = j;      L = lin_src; At = att_src; }
    else if (j < 8)  { t = 2; h = j - 4;  L = lin_src; At = att_src; }
    else if (j < 12) { t = 0; h = j - 8;  L = lin_dst; At = att_dst; }
    else             { t = 1; h = j - 12; L = lin_dst; At = att_dst; }
    int lt = l * 3 + t;
    float s = 0.f;
    for (int c = 0; c < 64; c++)
      s += b2f(L[((size_t)lt * 256 + k) * 256 + h * 64 + c]) * b2f(At[(lt * 4 + h) * 64 + c]);
    Wp[l * 4096 + k * 16 + j] = s;
  } else {
    int i2 = idx - 8192;
    l = i2 >> 11; int rem = i2 & 2047; k = rem >> 3; j = rem & 7;
    if (j < 4) { t = 0; h = j;     L = lin_src; At = att_src; }
    else       { t = 2; h = j - 4; L = lin_dst; At = att_dst; }
    int lt = l * 3 + t;
    float s = 0.f;
    for (int c = 0; c < 64; c++)
      s += b2f(L[((size_t)lt * 256 + k) * 256 + h * 64 + c]) * b2f(At[(lt * 4 + h) * 64 + c]);
    Wa[l * 2048 + k * 8 + j] = s;
  }
}

__global__ void transpose_kernel(const unsigned short* __restrict__ in,
                                 unsigned short* __restrict__ out, int K, int N, int batch)
{
  int idx = blockIdx.x * 256 + threadIdx.x;
  int total = batch * K * N;
  if (idx >= total) return;
  int b = idx / (K * N); int rem = idx % (K * N);
  int k = rem / N; int n = rem % N;
  out[(size_t)b * K * N + (size_t)n * K + k] = in[idx];
}

template <int NCOL>
__global__ __launch_bounds__(256) void al_kernel(const unsigned short* __restrict__ X, int rows,
                                                 const float* __restrict__ W, float* __restrict__ out)
{
  __shared__ __align__(16) float Ws[256 * NCOL];
  for (int i = threadIdx.x; i < 256 * NCOL; i += 256) Ws[i] = W[i];
  __syncthreads();
  int row = blockIdx.x * 256 + threadIdx.x;
  if (row >= rows) return;
  f32x4 acc[NCOL / 4];
#pragma unroll
  for (int jv = 0; jv < NCOL / 4; jv++) { acc[jv][0] = 0.f; acc[jv][1] = 0.f; acc[jv][2] = 0.f; acc[jv][3] = 0.f; }
  const unsigned short* xr = X + (size_t)row * 256;
  for (int k = 0; k < 256; k += 8) {
    uint4 pk = *(const uint4*)(xr + k);
    unsigned int uu[4] = {pk.x, pk.y, pk.z, pk.w};
#pragma unroll
    for (int e2 = 0; e2 < 4; e2++) {
      float x0 = b2f((unsigned short)(uu[e2] & 0xffffu));
      float x1 = b2f((unsigned short)(uu[e2] >> 16));
      int k0 = k + e2 * 2;
#pragma unroll
      for (int jv = 0; jv < NCOL / 4; jv++) {
        const f32x4 w0 = *(const f32x4*)&Ws[k0 * NCOL + jv * 4];
        const f32x4 w1 = *(const f32x4*)&Ws[(k0 + 1) * NCOL + jv * 4];
#pragma unroll
        for (int c = 0; c < 4; c++) acc[jv][c] += x0 * w0[c] + x1 * w1[c];
      }
    }
  }
#pragma unroll
  for (int jv = 0; jv < NCOL / 4; jv++)
    *(f32x4*)&out[(size_t)row * NCOL + jv * 4] = acc[jv];
}

__global__ void hist_kernel(const int* __restrict__ dst, int E, int* __restrict__ deg)
{
  int e = blockIdx.x * 256 + threadIdx.x;
  if (e < E) atomicAdd(&deg[dst[e]], 1);
}

__global__ __launch_bounds__(1024) void scan_kernel(const int* __restrict__ deg, int n, int E,
                                                    int* __restrict__ off, int* __restrict__ cur)
{
  __shared__ int sums[1024];
  int tid = threadIdx.x;
  int start = tid * 128;
  int s = 0;
  for (int i = 0; i < 128; i++) { int idx = start + i; if (idx < n) s += deg[idx]; }
  sums[tid] = s;
  __syncthreads();
  for (int d = 1; d < 1024; d <<= 1) {
    int v = (tid >= d) ? sums[tid - d] : 0;
    __syncthreads();
    sums[tid] += v;
    __syncthreads();
  }
  int run = sums[tid] - s;
  for (int i = 0; i < 128; i++) {
    int idx = start + i;
    if (idx < n) { off[idx] = run; cur[idx] = run; run += deg[idx]; }
  }
  if (tid == 0) off[n] = E;
}

__global__ void scatter_kernel(const int* __restrict__ src, const int* __restrict__ dst, int E,
                               int* __restrict__ cur, int* __restrict__ csr)
{
  int e = blockIdx.x * 256 + threadIdx.x;
  if (e < E) {
    int p = atomicAdd(&cur[dst[e]], 1);
    csr[p] = src[e];
  }
}

__global__ __launch_bounds__(256) void msg_paper_kernel(
    const unsigned short* __restrict__ hs0, const unsigned short* __restrict__ hs1,
    const float* __restrict__ al_p, const float* __restrict__ al_a,
    const int* __restrict__ off0, const int* __restrict__ csr0,
    const int* __restrict__ off1, const int* __restrict__ csr1,
    const unsigned short* __restrict__ bg0, const unsigned short* __restrict__ bg1,
    void* __restrict__ out, const int* __restrict__ flag)
{
  int n = blockIdx.x * 4 + (threadIdx.x >> 6);
  if (n >= NP) return;
  int lane = threadIdx.x & 63;
  int h = lane >> 4;
  int cb = lane * 4;
  float o0 = 0.f, o1 = 0.f, o2 = 0.f, o3 = 0.f;
  {
    float ald = al_p[n * 16 + 8 + h];
    int s = off0[n], e = off0[n + 1];
    float m = -1e30f, denom = 0.f, a0 = 0.f, a1 = 0.f, a2 = 0.f, a3 = 0.f;
    for (int i = s; i < e; i++) {
      int sv = csr0[i];
      float als = al_a[sv * 8 + h];
      float lg = als + ald; lg = lg > 0.f ? lg : 0.2f * lg;
      float mn = lg > m ? lg : m;
      float corr = __expf(m - mn);
      float p = __expf(lg - mn);
      m = mn;
      denom = denom * corr + p;
      const ushort4 hv = *(const ushort4*)(hs0 + (size_t)sv * 256 + cb);
      a0 = a0 * corr + p * b2f(hv.x);
      a1 = a1 * corr + p * b2f(hv.y);
      a2 = a2 * corr + p * b2f(hv.z);
      a3 = a3 * corr + p * b2f(hv.w);
    }
    float inv = denom > 0.f ? 1.f / denom : 0.f;
    o0 += a0 * inv; o1 += a1 * inv; o2 += a2 * inv; o3 += a3 * inv;
  }
  {
    float ald = al_p[n * 16 + 12 + h];
    int s = off1[n], e = off1[n + 1];
    float m = -1e30f, denom = 0.f, a0 = 0.f, a1 = 0.f, a2 = 0.f, a3 = 0.f;
    for (int i = s; i < e; i++) {
      int sv = csr1[i];
      float als = al_p[sv * 16 + h];
      float lg = als + ald; lg = lg > 0.f ? lg : 0.2f * lg;
      float mn = lg > m ? lg : m;
      float corr = __expf(m - mn);
      float p = __expf(lg - mn);
      m = mn;
      denom = denom * corr + p;
      const ushort4 hv = *(const ushort4*)(hs1 + (size_t)sv * 256 + cb);
      a0 = a0 * corr + p * b2f(hv.x);
      a1 = a1 * corr + p * b2f(hv.y);
      a2 = a2 * corr + p * b2f(hv.z);
      a3 = a3 * corr + p * b2f(hv.w);
    }
    float inv = denom > 0.f ? 1.f / denom : 0.f;
    o0 += a0 * inv; o1 += a1 * inv; o2 += a2 * inv; o3 += a3 * inv;
  }
  const ushort4 bv0 = *(const ushort4*)(bg0 + cb);
  const ushort4 bv1 = *(const ushort4*)(bg1 + cb);
  float v0 = o0 + b2f(bv0.x) + b2f(bv1.x); v0 = v0 > 0.f ? v0 : __expf(v0) - 1.f;
  float v1 = o1 + b2f(bv0.y) + b2f(bv1.y); v1 = v1 > 0.f ? v1 : __expf(v1) - 1.f;
  float v2 = o2 + b2f(bv0.z) + b2f(bv1.z); v2 = v2 > 0.f ? v2 : __expf(v2) - 1.f;
  float v3 = o3 + b2f(bv0.w) + b2f(bv1.w); v3 = v3 > 0.f ? v3 : __expf(v3) - 1.f;
  if (flag && *flag) {
    float* of = (float*)out;
    f32x4 ov = {v0, v1, v2, v3};
    *(f32x4*)(of + (size_t)n * 256 + cb) = ov;
  } else {
    unsigned short* ob = (unsigned short*)out;
    ushort4 ov; ov.x = f2b(v0); ov.y = f2b(v1); ov.z = f2b(v2); ov.w = f2b(v3);
    *(ushort4*)(ob + (size_t)n * 256 + cb) = ov;
  }
}

// FINAL!=0: out points at d_out base; apply NP*256-element offset per dtype.
template <int FINAL>
__global__ __launch_bounds__(256) void msg_author_kernel(
    const unsigned short* __restrict__ hs2,
    const float* __restrict__ al_p, const float* __restrict__ al_a,
    const int* __restrict__ off2, const int* __restrict__ csr2,
    const unsigned short* __restrict__ bg2, void* __restrict__ out,
    const int* __restrict__ flag)
{
  int n = blockIdx.x * 4 + (threadIdx.x >> 6);
  if (n >= NA) return;
  int lane = threadIdx.x & 63;
  int h = lane >> 4;
  int cb = lane * 4;
  float ald = al_a[n * 8 + 4 + h];
  int s = off2[n], e = off2[n + 1];
  float m = -1e30f, denom = 0.f, a0 = 0.f, a1 = 0.f, a2 = 0.f, a3 = 0.f;
  for (int i = s; i < e; i++) {
    int sv = csr2[i];
    float als = al_p[sv * 16 + 4 + h];
    float lg = als + ald; lg = lg > 0.f ? lg : 0.2f * lg;
    float mn = lg > m ? lg : m;
    float corr = __expf(m - mn);
    float p = __expf(lg - mn);
    m = mn;
    denom = denom * corr + p;
    const ushort4 hv = *(const ushort4*)(hs2 + (size_t)sv * 256 + cb);
    a0 = a0 * corr + p * b2f(hv.x);
    a1 = a1 * corr + p * b2f(hv.y);
    a2 = a2 * corr + p * b2f(hv.z);
    a3 = a3 * corr + p * b2f(hv.w);
  }
  float inv = denom > 0.f ? 1.f / denom : 0.f;
  const ushort4 bv = *(const ushort4*)(bg2 + cb);
  float v0 = a0 * inv + b2f(bv.x); v0 = v0 > 0.f ? v0 : __expf(v0) - 1.f;
  float v1 = a1 * inv + b2f(bv.y); v1 = v1 > 0.f ? v1 : __expf(v1) - 1.f;
  float v2 = a2 * inv + b2f(bv.z); v2 = v2 > 0.f ? v2 : __expf(v2) - 1.f;
  float v3 = a3 * inv + b2f(bv.w); v3 = v3 > 0.f ? v3 : __expf(v3) - 1.f;
  size_t elem = (size_t)n * 256 + cb + (FINAL ? (size_t)NP * 256 : 0);
  if (FINAL && flag && *flag) {
    float* of = (float*)out;
    f32x4 ov = {v0, v1, v2, v3};
    *(f32x4*)(of + elem) = ov;
  } else {
    unsigned short* ob = (unsigned short*)out;
    ushort4 ov; ov.x = f2b(v0); ov.y = f2b(v1); ov.z = f2b(v2); ov.w = f2b(v3);
    *(ushort4*)(ob + elem) = ov;
  }
}

extern "C" void kernel_launch(void* const* d_in, const int* in_sizes, int n_in,
                              void* d_out, int out_size, void* d_ws, size_t ws_size,
                              hipStream_t stream)
{
  const unsigned short* x_paper  = (const unsigned short*)d_in[0];
  const unsigned short* x_author = (const unsigned short*)d_in[1];
  const unsigned short* W_in_p   = (const unsigned short*)d_in[2];
  const unsigned short* b_in_p   = (const unsigned short*)d_in[3];
  const unsigned short* W_in_a   = (const unsigned short*)d_in[4];
  const unsigned short* b_in_a   = (const unsigned short*)d_in[5];
  const unsigned short* lin_src  = (const unsigned short*)d_in[6];
  const unsigned short* lin_dst  = (const unsigned short*)d_in[7];
  const unsigned short* att_src  = (const unsigned short*)d_in[8];
  const unsigned short* att_dst  = (const unsigned short*)d_in[9];
  const unsigned short* bias_gat = (const unsigned short*)d_in[10];
  const int* writes_src = (const int*)d_in[11];
  const int* writes_dst = (const int*)d_in[12];
  const int* cites_src  = (const int*)d_in[13];
  const int* cites_dst  = (const int*)d_in[14];
  const int* wb_src     = (const int*)d_in[15];
  const int* wb_dst     = (const int*)d_in[16];

  char* base = (char*)d_ws;
  size_t cur = 0;
  auto take = [&](size_t bytes) -> char* {
    char* p = base + cur;
    cur += (bytes + 255) & ~(size_t)255;
    return p;
  };

  int* flag = (int*)take(256);
  unsigned short* cxp   = (unsigned short*)take((size_t)NP * 128 * 2);
  unsigned short* cxa   = (unsigned short*)take((size_t)NA * 128 * 2);
  unsigned short* cWinP = (unsigned short*)take(128 * 256 * 2);
  unsigned short* cWinA = (unsigned short*)take(128 * 256 * 2);
  unsigned short* cbinP = (unsigned short*)take(256 * 2);
  unsigned short* cbinA = (unsigned short*)take(256 * 2);
  unsigned short* clins = (unsigned short*)take((size_t)6 * 65536 * 2);
  unsigned short* clind = (unsigned short*)take((size_t)6 * 65536 * 2);
  unsigned short* catts = (unsigned short*)take(1536 * 2);
  unsigned short* cattd = (unsigned short*)take(1536 * 2);
  unsigned short* cbias = (unsigned short*)take(1536 * 2);

  unsigned short* xp  = (unsigned short*)take((size_t)NP * 256 * 2);
  unsigned short* xa  = (unsigned short*)take((size_t)NA * 256 * 2);
  unsigned short* hs0 = (unsigned short*)take((size_t)NA * 256 * 2);
  unsigned short* hs1 = (unsigned short*)take((size_t)NP * 256 * 2);
  unsigned short* hs2 = (unsigned short*)take((size_t)NP * 256 * 2);
  float* al_p = (float*)take((size_t)NP * 16 * 4);
  float* al_a = (float*)take((size_t)NA * 8 * 4);
  float* Wp   = (float*)take(2 * 256 * 16 * 4);
  float* Wa   = (float*)take(2 * 256 * 8 * 4);
  unsigned short* WinpT = (unsigned short*)take(256 * 128 * 2);
  unsigned short* WinaT = (unsigned short*)take(256 * 128 * 2);
  unsigned short* linsT = (unsigned short*)take((size_t)6 * 65536 * 2);
  int* off0 = (int*)take((size_t)(NP + 1) * 4);
  int* cur0 = (int*)take((size_t)NP * 4);
  int* csr0 = (int*)take((size_t)NE * 4);
  int* off1 = (int*)take((size_t)(NP + 1) * 4);
  int* cur1 = (int*)take((size_t)NP * 4);
  int* csr1 = (int*)take((size_t)NE * 4);
  int* off2 = (int*)take((size_t)(NA + 1) * 4);
  int* cur2 = (int*)take((size_t)NA * 4);
  int* csr2 = (int*)take((size_t)NE * 4);
  int* deg0 = (int*)take((size_t)NP * 4);
  int* deg1 = (int*)take((size_t)NP * 4);
  int* deg2 = (int*)take((size_t)NA * 4);

  probe_kernel<<<1, 256, 0, stream>>>(x_paper, flag);

  auto conv = [&](const unsigned short* s, unsigned short* d, int n) {
    conv_kernel<<<(n + 255) / 256, 256, 0, stream>>>(s, d, n, flag);
  };
  conv(x_paper, cxp, NP * 128);
  conv(x_author, cxa, NA * 128);
  conv(W_in_p, cWinP, 128 * 256);
  conv(W_in_a, cWinA, 128 * 256);
  conv(b_in_p, cbinP, 256);
  conv(b_in_a, cbinA, 256);
  conv(lin_src, clins, 6 * 65536);
  conv(lin_dst, clind, 6 * 65536);
  conv(att_src, catts, 1536);
  conv(att_dst, cattd, 1536);
  conv(bias_gat, cbias, 1536);

  hipMemsetAsync(deg0, 0, (size_t)NP * 4, stream);
  hipMemsetAsync(deg1, 0, (size_t)NP * 4, stream);
  hipMemsetAsync(deg2, 0, (size_t)NA * 4, stream);

  fold_kernel<<<48, 256, 0, stream>>>(clins, clind, catts, cattd, Wp, Wa);
  transpose_kernel<<<(6 * 65536) / 256, 256, 0, stream>>>(clins, linsT, 256, 256, 6);
  transpose_kernel<<<(128 * 256) / 256, 256, 0, stream>>>(cWinP, WinpT, 128, 256, 1);
  transpose_kernel<<<(128 * 256) / 256, 256, 0, stream>>>(cWinA, WinaT, 128, 256, 1);

  hist_kernel<<<(NE + 255) / 256, 256, 0, stream>>>(writes_dst, NE, deg0);
  hist_kernel<<<(NE + 255) / 256, 256, 0, stream>>>(cites_dst, NE, deg1);
  hist_kernel<<<(NE + 255) / 256, 256, 0, stream>>>(wb_dst, NE, deg2);
  scan_kernel<<<1, 1024, 0, stream>>>(deg0, NP, NE, off0, cur0);
  scan_kernel<<<1, 1024, 0, stream>>>(deg1, NP, NE, off1, cur1);
  scan_kernel<<<1, 1024, 0, stream>>>(deg2, NA, NE, off2, cur2);
  scatter_kernel<<<(NE + 255) / 256, 256, 0, stream>>>(writes_src, writes_dst, NE, cur0, csr0);
  scatter_kernel<<<(NE + 255) / 256, 256, 0, stream>>>(cites_src, cites_dst, NE, cur1, csr1);
  scatter_kernel<<<(NE + 255) / 256, 256, 0, stream>>>(wb_src, wb_dst, NE, cur2, csr2);

  gemm256<1><<<dim3((NP + 127) / 128, 2), 256, 0, stream>>>(cxp, WinpT, xp, NP, 128, cbinP);
  gemm256<1><<<dim3((NA + 127) / 128, 2), 256, 0, stream>>>(cxa, WinaT, xa, NA, 128, cbinA);

  for (int l = 0; l < 2; ++l) {
    gemm256<0><<<dim3((NA + 127) / 128, 2), 256, 0, stream>>>(xa, linsT + (size_t)(l * 3 + 0) * 65536, hs0, NA, 256, nullptr);
    gemm256<0><<<dim3((NP + 127) / 128, 2), 256, 0, stream>>>(xp, linsT + (size_t)(l * 3 + 1) * 65536, hs1, NP, 256, nullptr);
    gemm256<0><<<dim3((NP + 127) / 128, 2), 256, 0, stream>>>(xp, linsT + (size_t)(l * 3 + 2) * 65536, hs2, NP, 256, nullptr);
    al_kernel<16><<<(NP + 255) / 256, 256, 0, stream>>>(xp, NP, Wp + l * 4096, al_p);
    al_kernel<8><<<(NA + 255) / 256, 256, 0, stream>>>(xa, NA, Wa + l * 2048, al_a);
    if (l == 0) {
      msg_paper_kernel<<<NP / 4, 256, 0, stream>>>(hs0, hs1, al_p, al_a, off0, csr0, off1, csr1,
          cbias + 0 * 256, cbias + 1 * 256, xp, nullptr);
      msg_author_kernel<0><<<NA / 4, 256, 0, stream>>>(hs2, al_p, al_a, off2, csr2,
          cbias + 2 * 256, xa, nullptr);
    } else {
      msg_paper_kernel<<<NP / 4, 256, 0, stream>>>(hs0, hs1, al_p, al_a, off0, csr0, off1, csr1,
          cbias + 3 * 256, cbias + 4 * 256, d_out, flag);
      msg_author_kernel<1><<<NA / 4, 256, 0, stream>>>(hs2, al_p, al_a, off2, csr2,
          cbias + 5 * 256, d_out, flag);
    }
  }
}

// Round 4
// 1262.536 us; speedup vs baseline: 1.4472x; 1.4472x over previous
//
#include <hip/hip_runtime.h>

// HeteroGAT on MI355X. Round 4: replace the 240µs single-block scan with a
// 3-phase hierarchical scan (partial sums -> wave scan of block sums -> emit).
// Everything else identical to the passing round-3 pipeline.

#define NP 100000
#define NA 50000
#define NE 250000

typedef __attribute__((ext_vector_type(8))) short short8;
typedef __attribute__((ext_vector_type(4))) float f32x4;

__device__ __forceinline__ float b2f(unsigned short u) {
  union { unsigned int i; float f; } v; v.i = ((unsigned int)u) << 16; return v.f;
}
__device__ __forceinline__ unsigned short f2b(float f) {
  union { float f; unsigned int i; } v; v.f = f;
  unsigned int u = v.i;
  return (unsigned short)((u + 0x7fffu + ((u >> 16) & 1u)) >> 16);
}

__global__ void probe_kernel(const unsigned short* __restrict__ x, int* __restrict__ flag)
{
  __shared__ int cnt;
  if (threadIdx.x == 0) cnt = 0;
  __syncthreads();
  int c = 0;
  for (int i = threadIdx.x; i < 4096; i += 256) {
    unsigned int e = (x[i] >> 7) & 0xFFu;
    if (e >= 0xC0u) c++;
  }
  atomicAdd(&cnt, c);
  __syncthreads();
  if (threadIdx.x == 0) *flag = (cnt > 64) ? 1 : 0;   // 1 = inputs are fp32
}

__global__ void conv_kernel(const unsigned short* __restrict__ src,
                            unsigned short* __restrict__ dst, int n,
                            const int* __restrict__ flag)
{
  int i = blockIdx.x * 256 + threadIdx.x;
  if (i >= n) return;
  if (*flag) {
    const float* f = (const float*)src;
    dst[i] = f2b(f[i]);
  } else {
    dst[i] = src[i];
  }
}

template <int RELU>
__global__ __launch_bounds__(256) void gemm256(
    const unsigned short* __restrict__ A, const unsigned short* __restrict__ BT,
    unsigned short* __restrict__ C, int M, int K, const unsigned short* __restrict__ bias)
{
  __shared__ __align__(16) unsigned short As[128 * 64];
  __shared__ __align__(16) unsigned short Bs[128 * 64];
  const int t = threadIdx.x;
  const int lane = t & 63;
  const int w = t >> 6;
  const int wr = w >> 1, wc = w & 1;
  const int quad = lane >> 4;
  const int l16 = lane & 15;
  const int m0 = blockIdx.x * 128;
  const int n0 = blockIdx.y * 128;

  f32x4 acc[4][4];
#pragma unroll
  for (int i = 0; i < 4; i++)
#pragma unroll
    for (int j = 0; j < 4; j++) { acc[i][j][0] = 0.f; acc[i][j][1] = 0.f; acc[i][j][2] = 0.f; acc[i][j][3] = 0.f; }

  const int nkc = K >> 6;
  for (int kc = 0; kc < nkc; ++kc) {
    uint4 av[4], bv[4];
#pragma unroll
    for (int i = 0; i < 4; i++) {
      int chunk = i * 256 + t;
      int r = chunk >> 3, c8 = chunk & 7;
      int gr = m0 + r; gr = gr < M ? gr : (M - 1);
      av[i] = *(const uint4*)(A + (size_t)gr * K + (kc * 64 + c8 * 8));
      bv[i] = *(const uint4*)(BT + (size_t)(n0 + r) * K + (kc * 64 + c8 * 8));
    }
    __syncthreads();
#pragma unroll
    for (int i = 0; i < 4; i++) {
      int chunk = i * 256 + t;
      *(uint4*)(As + chunk * 8) = av[i];
      *(uint4*)(Bs + chunk * 8) = bv[i];
    }
    __syncthreads();
#pragma unroll
    for (int ks = 0; ks < 2; ++ks) {
      short8 af[4], bq[4];
#pragma unroll
      for (int i = 0; i < 4; i++)
        af[i] = *(const short8*)(As + (wr * 64 + i * 16 + l16) * 64 + ks * 32 + quad * 8);
#pragma unroll
      for (int j = 0; j < 4; j++)
        bq[j] = *(const short8*)(Bs + (wc * 64 + j * 16 + l16) * 64 + ks * 32 + quad * 8);
#pragma unroll
      for (int i = 0; i < 4; i++)
#pragma unroll
        for (int j = 0; j < 4; j++)
          acc[i][j] = __builtin_amdgcn_mfma_f32_16x16x32_bf16(af[i], bq[j], acc[i][j], 0, 0, 0);
    }
  }
#pragma unroll
  for (int j = 0; j < 4; j++) {
    int col = n0 + wc * 64 + j * 16 + l16;
    float bv2 = bias ? b2f(bias[col]) : 0.f;
#pragma unroll
    for (int i = 0; i < 4; i++) {
      int rbase = m0 + wr * 64 + i * 16 + quad * 4;
#pragma unroll
      for (int r = 0; r < 4; r++) {
        int row = rbase + r;
        if (row < M) {
          float v = acc[i][j][r] + bv2;
          if (RELU) v = v > 0.f ? v : 0.f;
          C[(size_t)row * 256 + col] = f2b(v);
        }
      }
    }
  }
}

// Wp cols: 0-3 al_s(t=1), 4-7 al_s(t=2), 8-11 al_d(t=0), 12-15 al_d(t=1)
// Wa cols: 0-3 al_s(t=0), 4-7 al_d(t=2)
__global__ void fold_kernel(const unsigned short* __restrict__ lin_src,
                            const unsigned short* __restrict__ lin_dst,
                            const unsigned short* __restrict__ att_src,
                            const unsigned short* __restrict__ att_dst,
                            float* __restrict__ Wp, float* __restrict__ Wa)
{
  int idx = blockIdx.x * 256 + threadIdx.x;
  if (idx >= 12288) return;
  const unsigned short *L, *At;
  int l, k, j, t, h;
  if (idx < 8192) {
    l = idx >> 12; int rem = idx & 4095; k = rem >> 4; j = rem & 15;
    if (j < 4)       { t = 1; h = j;      L = lin_src; At = att_src; }
    else if (j < 8)  { t = 2; h = j - 4;  L = lin_src; At = att_src; }
    else if (j < 12) { t = 0; h = j - 8;  L = lin_dst; At = att_dst; }
    else             { t = 1; h = j - 12; L = lin_dst; At = att_dst; }
    int lt = l * 3 + t;
    float s = 0.f;
    for (int c = 0; c < 64; c++)
      s += b2f(L[((size_t)lt * 256 + k) * 256 + h * 64 + c]) * b2f(At[(lt * 4 + h) * 64 + c]);
    Wp[l * 4096 + k * 16 + j] = s;
  } else {
    int i2 = idx - 8192;
    l = i2 >> 11; int rem = i2 & 2047; k = rem >> 3; j = rem & 7;
    if (j < 4) { t = 0; h = j;     L = lin_src; At = att_src; }
    else       { t = 2; h = j - 4; L = lin_dst; At = att_dst; }
    int lt = l * 3 + t;
    float s = 0.f;
    for (int c = 0; c < 64; c++)
      s += b2f(L[((size_t)lt * 256 + k) * 256 + h * 64 + c]) * b2f(At[(lt * 4 + h) * 64 + c]);
    Wa[l * 2048 + k * 8 + j] = s;
  }
}

__global__ void transpose_kernel(const unsigned short* __restrict__ in,
                                 unsigned short* __restrict__ out, int K, int N, int batch)
{
  int idx = blockIdx.x * 256 + threadIdx.x;
  int total = batch * K * N;
  if (idx >= total) return;
  int b = idx / (K * N); int rem = idx % (K * N);
  int k = rem / N; int n = rem % N;
  out[(size_t)b * K * N + (size_t)n * K + k] = in[idx];
}

template <int NCOL>
__global__ __launch_bounds__(256) void al_kernel(const unsigned short* __restrict__ X, int rows,
                                                 const float* __restrict__ W, float* __restrict__ out)
{
  __shared__ __align__(16) float Ws[256 * NCOL];
  for (int i = threadIdx.x; i < 256 * NCOL; i += 256) Ws[i] = W[i];
  __syncthreads();
  int row = blockIdx.x * 256 + threadIdx.x;
  if (row >= rows) return;
  f32x4 acc[NCOL / 4];
#pragma unroll
  for (int jv = 0; jv < NCOL / 4; jv++) { acc[jv][0] = 0.f; acc[jv][1] = 0.f; acc[jv][2] = 0.f; acc[jv][3] = 0.f; }
  const unsigned short* xr = X + (size_t)row * 256;
  for (int k = 0; k < 256; k += 8) {
    uint4 pk = *(const uint4*)(xr + k);
    unsigned int uu[4] = {pk.x, pk.y, pk.z, pk.w};
#pragma unroll
    for (int e2 = 0; e2 < 4; e2++) {
      float x0 = b2f((unsigned short)(uu[e2] & 0xffffu));
      float x1 = b2f((unsigned short)(uu[e2] >> 16));
      int k0 = k + e2 * 2;
#pragma unroll
      for (int jv = 0; jv < NCOL / 4; jv++) {
        const f32x4 w0 = *(const f32x4*)&Ws[k0 * NCOL + jv * 4];
        const f32x4 w1 = *(const f32x4*)&Ws[(k0 + 1) * NCOL + jv * 4];
#pragma unroll
        for (int c = 0; c < 4; c++) acc[jv][c] += x0 * w0[c] + x1 * w1[c];
      }
    }
  }
#pragma unroll
  for (int jv = 0; jv < NCOL / 4; jv++)
    *(f32x4*)&out[(size_t)row * NCOL + jv * 4] = acc[jv];
}

__global__ void hist_kernel(const int* __restrict__ dst, int E, int* __restrict__ deg)
{
  int e = blockIdx.x * 256 + threadIdx.x;
  if (e < E) atomicAdd(&deg[dst[e]], 1);
}

// ---------------- hierarchical scan: 2048 elements per 256-thread block
__global__ __launch_bounds__(256) void scan_partial_kernel(const int* __restrict__ deg, int n,
                                                           int* __restrict__ bsum)
{
  int tid = threadIdx.x;
  int base = blockIdx.x * 2048 + tid * 8;
  int s = 0;
#pragma unroll
  for (int i = 0; i < 8; i++) { int idx = base + i; if (idx < n) s += deg[idx]; }
  __shared__ int red[256];
  red[tid] = s;
  __syncthreads();
  for (int d = 128; d > 0; d >>= 1) {
    if (tid < d) red[tid] += red[tid + d];
    __syncthreads();
  }
  if (tid == 0) bsum[blockIdx.x] = red[0];
}

// one wave; nb <= 64. In-place exclusive scan of block sums.
__global__ void scan_bsum_kernel(int* __restrict__ bsum, int nb)
{
  int lane = threadIdx.x;
  int orig = (lane < nb) ? bsum[lane] : 0;
  int v = orig;
  for (int d = 1; d < 64; d <<= 1) {
    int t = __shfl_up(v, d);
    if (lane >= d) v += t;
  }
  if (lane < nb) bsum[lane] = v - orig;   // exclusive
}

__global__ __launch_bounds__(256) void scan_emit_kernel(const int* __restrict__ deg, int n, int E,
                                                        const int* __restrict__ bsum,
                                                        int* __restrict__ off, int* __restrict__ cur)
{
  int tid = threadIdx.x;
  int base = blockIdx.x * 2048 + tid * 8;
  int vals[8]; int s = 0;
#pragma unroll
  for (int i = 0; i < 8; i++) { int idx = base + i; vals[i] = (idx < n) ? deg[idx] : 0; s += vals[i]; }
  __shared__ int sh[256];
  sh[tid] = s;
  __syncthreads();
  for (int d = 1; d < 256; d <<= 1) {
    int t = (tid >= d) ? sh[tid - d] : 0;
    __syncthreads();
    sh[tid] += t;
    __syncthreads();
  }
  int run = bsum[blockIdx.x] + sh[tid] - s;   // exclusive prefix for this thread's chunk
#pragma unroll
  for (int i = 0; i < 8; i++) {
    int idx = base + i;
    if (idx < n) { off[idx] = run; cur[idx] = run; run += vals[i]; }
  }
  if (blockIdx.x == 0 && tid == 0) off[n] = E;
}

__global__ void scatter_kernel(const int* __restrict__ src, const int* __restrict__ dst, int E,
                               int* __restrict__ cur, int* __restrict__ csr)
{
  int e = blockIdx.x * 256 + threadIdx.x;
  if (e < E) {
    int p = atomicAdd(&cur[dst[e]], 1);
    csr[p] = src[e];
  }
}

__global__ __launch_bounds__(256) void msg_paper_kernel(
    const unsigned short* __restrict__ hs0, const unsigned short* __restrict__ hs1,
    const float* __restrict__ al_p, const float* __restrict__ al_a,
    const int* __restrict__ off0, const int* __restrict__ csr0,
    const int* __restrict__ off1, const int* __restrict__ csr1,
    const unsigned short* __restrict__ bg0, const unsigned short* __restrict__ bg1,
    void* __restrict__ out, const int* __restrict__ flag)
{
  int n = blockIdx.x * 4 + (threadIdx.x >> 6);
  if (n >= NP) return;
  int lane = threadIdx.x & 63;
  int h = lane >> 4;
  int cb = lane * 4;
  float o0 = 0.f, o1 = 0.f, o2 = 0.f, o3 = 0.f;
  {
    float ald = al_p[n * 16 + 8 + h];
    int s = off0[n], e = off0[n + 1];
    float m = -1e30f, denom = 0.f, a0 = 0.f, a1 = 0.f, a2 = 0.f, a3 = 0.f;
    for (int i = s; i < e; i++) {
      int sv = csr0[i];
      float als = al_a[sv * 8 + h];
      float lg = als + ald; lg = lg > 0.f ? lg : 0.2f * lg;
      float mn = lg > m ? lg : m;
      float corr = __expf(m - mn);
      float p = __expf(lg - mn);
      m = mn;
      denom = denom * corr + p;
      const ushort4 hv = *(const ushort4*)(hs0 + (size_t)sv * 256 + cb);
      a0 = a0 * corr + p * b2f(hv.x);
      a1 = a1 * corr + p * b2f(hv.y);
      a2 = a2 * corr + p * b2f(hv.z);
      a3 = a3 * corr + p * b2f(hv.w);
    }
    float inv = denom > 0.f ? 1.f / denom : 0.f;
    o0 += a0 * inv; o1 += a1 * inv; o2 += a2 * inv; o3 += a3 * inv;
  }
  {
    float ald = al_p[n * 16 + 12 + h];
    int s = off1[n], e = off1[n + 1];
    float m = -1e30f, denom = 0.f, a0 = 0.f, a1 = 0.f, a2 = 0.f, a3 = 0.f;
    for (int i = s; i < e; i++) {
      int sv = csr1[i];
      float als = al_p[sv * 16 + h];
      float lg = als + ald; lg = lg > 0.f ? lg : 0.2f * lg;
      float mn = lg > m ? lg : m;
      float corr = __expf(m - mn);
      float p = __expf(lg - mn);
      m = mn;
      denom = denom * corr + p;
      const ushort4 hv = *(const ushort4*)(hs1 + (size_t)sv * 256 + cb);
      a0 = a0 * corr + p * b2f(hv.x);
      a1 = a1 * corr + p * b2f(hv.y);
      a2 = a2 * corr + p * b2f(hv.z);
      a3 = a3 * corr + p * b2f(hv.w);
    }
    float inv = denom > 0.f ? 1.f / denom : 0.f;
    o0 += a0 * inv; o1 += a1 * inv; o2 += a2 * inv; o3 += a3 * inv;
  }
  const ushort4 bv0 = *(const ushort4*)(bg0 + cb);
  const ushort4 bv1 = *(const ushort4*)(bg1 + cb);
  float v0 = o0 + b2f(bv0.x) + b2f(bv1.x); v0 = v0 > 0.f ? v0 : __expf(v0) - 1.f;
  float v1 = o1 + b2f(bv0.y) + b2f(bv1.y); v1 = v1 > 0.f ? v1 : __expf(v1) - 1.f;
  float v2 = o2 + b2f(bv0.z) + b2f(bv1.z); v2 = v2 > 0.f ? v2 : __expf(v2) - 1.f;
  float v3 = o3 + b2f(bv0.w) + b2f(bv1.w); v3 = v3 > 0.f ? v3 : __expf(v3) - 1.f;
  if (flag && *flag) {
    float* of = (float*)out;
    f32x4 ov = {v0, v1, v2, v3};
    *(f32x4*)(of + (size_t)n * 256 + cb) = ov;
  } else {
    unsigned short* ob = (unsigned short*)out;
    ushort4 ov; ov.x = f2b(v0); ov.y = f2b(v1); ov.z = f2b(v2); ov.w = f2b(v3);
    *(ushort4*)(ob + (size_t)n * 256 + cb) = ov;
  }
}

template <int FINAL>
__global__ __launch_bounds__(256) void msg_author_kernel(
    const unsigned short* __restrict__ hs2,
    const float* __restrict__ al_p, const float* __restrict__ al_a,
    const int* __restrict__ off2, const int* __restrict__ csr2,
    const unsigned short* __restrict__ bg2, void* __restrict__ out,
    const int* __restrict__ flag)
{
  int n = blockIdx.x * 4 + (threadIdx.x >> 6);
  if (n >= NA) return;
  int lane = threadIdx.x & 63;
  int h = lane >> 4;
  int cb = lane * 4;
  float ald = al_a[n * 8 + 4 + h];
  int s = off2[n], e = off2[n + 1];
  float m = -1e30f, denom = 0.f, a0 = 0.f, a1 = 0.f, a2 = 0.f, a3 = 0.f;
  for (int i = s; i < e; i++) {
    int sv = csr2[i];
    float als = al_p[sv * 16 + 4 + h];
    float lg = als + ald; lg = lg > 0.f ? lg : 0.2f * lg;
    float mn = lg > m ? lg : m;
    float corr = __expf(m - mn);
    float p = __expf(lg - mn);
    m = mn;
    denom = denom * corr + p;
    const ushort4 hv = *(const ushort4*)(hs2 + (size_t)sv * 256 + cb);
    a0 = a0 * corr + p * b2f(hv.x);
    a1 = a1 * corr + p * b2f(hv.y);
    a2 = a2 * corr + p * b2f(hv.z);
    a3 = a3 * corr + p * b2f(hv.w);
  }
  float inv = denom > 0.f ? 1.f / denom : 0.f;
  const ushort4 bv = *(const ushort4*)(bg2 + cb);
  float v0 = a0 * inv + b2f(bv.x); v0 = v0 > 0.f ? v0 : __expf(v0) - 1.f;
  float v1 = a1 * inv + b2f(bv.y); v1 = v1 > 0.f ? v1 : __expf(v1) - 1.f;
  float v2 = a2 * inv + b2f(bv.z); v2 = v2 > 0.f ? v2 : __expf(v2) - 1.f;
  float v3 = a3 * inv + b2f(bv.w); v3 = v3 > 0.f ? v3 : __expf(v3) - 1.f;
  size_t elem = (size_t)n * 256 + cb + (FINAL ? (size_t)NP * 256 : 0);
  if (FINAL && flag && *flag) {
    float* of = (float*)out;
    f32x4 ov = {v0, v1, v2, v3};
    *(f32x4*)(of + elem) = ov;
  } else {
    unsigned short* ob = (unsigned short*)out;
    ushort4 ov; ov.x = f2b(v0); ov.y = f2b(v1); ov.z = f2b(v2); ov.w = f2b(v3);
    *(ushort4*)(ob + elem) = ov;
  }
}

extern "C" void kernel_launch(void* const* d_in, const int* in_sizes, int n_in,
                              void* d_out, int out_size, void* d_ws, size_t ws_size,
                              hipStream_t stream)
{
  const unsigned short* x_paper  = (const unsigned short*)d_in[0];
  const unsigned short* x_author = (const unsigned short*)d_in[1];
  const unsigned short* W_in_p   = (const unsigned short*)d_in[2];
  const unsigned short* b_in_p   = (const unsigned short*)d_in[3];
  const unsigned short* W_in_a   = (const unsigned short*)d_in[4];
  const unsigned short* b_in_a   = (const unsigned short*)d_in[5];
  const unsigned short* lin_src  = (const unsigned short*)d_in[6];
  const unsigned short* lin_dst  = (const unsigned short*)d_in[7];
  const unsigned short* att_src  = (const unsigned short*)d_in[8];
  const unsigned short* att_dst  = (const unsigned short*)d_in[9];
  const unsigned short* bias_gat = (const unsigned short*)d_in[10];
  const int* writes_src = (const int*)d_in[11];
  const int* writes_dst = (const int*)d_in[12];
  const int* cites_src  = (const int*)d_in[13];
  const int* cites_dst  = (const int*)d_in[14];
  const int* wb_src     = (const int*)d_in[15];
  const int* wb_dst     = (const int*)d_in[16];

  char* base = (char*)d_ws;
  size_t cur = 0;
  auto take = [&](size_t bytes) -> char* {
    char* p = base + cur;
    cur += (bytes + 255) & ~(size_t)255;
    return p;
  };

  int* flag = (int*)take(256);
  unsigned short* cxp   = (unsigned short*)take((size_t)NP * 128 * 2);
  unsigned short* cxa   = (unsigned short*)take((size_t)NA * 128 * 2);
  unsigned short* cWinP = (unsigned short*)take(128 * 256 * 2);
  unsigned short* cWinA = (unsigned short*)take(128 * 256 * 2);
  unsigned short* cbinP = (unsigned short*)take(256 * 2);
  unsigned short* cbinA = (unsigned short*)take(256 * 2);
  unsigned short* clins = (unsigned short*)take((size_t)6 * 65536 * 2);
  unsigned short* clind = (unsigned short*)take((size_t)6 * 65536 * 2);
  unsigned short* catts = (unsigned short*)take(1536 * 2);
  unsigned short* cattd = (unsigned short*)take(1536 * 2);
  unsigned short* cbias = (unsigned short*)take(1536 * 2);

  unsigned short* xp  = (unsigned short*)take((size_t)NP * 256 * 2);
  unsigned short* xa  = (unsigned short*)take((size_t)NA * 256 * 2);
  unsigned short* hs0 = (unsigned short*)take((size_t)NA * 256 * 2);
  unsigned short* hs1 = (unsigned short*)take((size_t)NP * 256 * 2);
  unsigned short* hs2 = (unsigned short*)take((size_t)NP * 256 * 2);
  float* al_p = (float*)take((size_t)NP * 16 * 4);
  float* al_a = (float*)take((size_t)NA * 8 * 4);
  float* Wp   = (float*)take(2 * 256 * 16 * 4);
  float* Wa   = (float*)take(2 * 256 * 8 * 4);
  unsigned short* WinpT = (unsigned short*)take(256 * 128 * 2);
  unsigned short* WinaT = (unsigned short*)take(256 * 128 * 2);
  unsigned short* linsT = (unsigned short*)take((size_t)6 * 65536 * 2);
  int* off0 = (int*)take((size_t)(NP + 1) * 4);
  int* cur0 = (int*)take((size_t)NP * 4);
  int* csr0 = (int*)take((size_t)NE * 4);
  int* off1 = (int*)take((size_t)(NP + 1) * 4);
  int* cur1 = (int*)take((size_t)NP * 4);
  int* csr1 = (int*)take((size_t)NE * 4);
  int* off2 = (int*)take((size_t)(NA + 1) * 4);
  int* cur2 = (int*)take((size_t)NA * 4);
  int* csr2 = (int*)take((size_t)NE * 4);
  int* deg0 = (int*)take((size_t)NP * 4);
  int* deg1 = (int*)take((size_t)NP * 4);
  int* deg2 = (int*)take((size_t)NA * 4);
  int* bsum0 = (int*)take(64 * 4);
  int* bsum1 = (int*)take(64 * 4);
  int* bsum2 = (int*)take(64 * 4);

  probe_kernel<<<1, 256, 0, stream>>>(x_paper, flag);

  auto conv = [&](const unsigned short* s, unsigned short* d, int n) {
    conv_kernel<<<(n + 255) / 256, 256, 0, stream>>>(s, d, n, flag);
  };
  conv(x_paper, cxp, NP * 128);
  conv(x_author, cxa, NA * 128);
  conv(W_in_p, cWinP, 128 * 256);
  conv(W_in_a, cWinA, 128 * 256);
  conv(b_in_p, cbinP, 256);
  conv(b_in_a, cbinA, 256);
  conv(lin_src, clins, 6 * 65536);
  conv(lin_dst, clind, 6 * 65536);
  conv(att_src, catts, 1536);
  conv(att_dst, cattd, 1536);
  conv(bias_gat, cbias, 1536);

  hipMemsetAsync(deg0, 0, (size_t)NP * 4, stream);
  hipMemsetAsync(deg1, 0, (size_t)NP * 4, stream);
  hipMemsetAsync(deg2, 0, (size_t)NA * 4, stream);

  fold_kernel<<<48, 256, 0, stream>>>(clins, clind, catts, cattd, Wp, Wa);
  transpose_kernel<<<(6 * 65536) / 256, 256, 0, stream>>>(clins, linsT, 256, 256, 6);
  transpose_kernel<<<(128 * 256) / 256, 256, 0, stream>>>(cWinP, WinpT, 128, 256, 1);
  transpose_kernel<<<(128 * 256) / 256, 256, 0, stream>>>(cWinA, WinaT, 128, 256, 1);

  hist_kernel<<<(NE + 255) / 256, 256, 0, stream>>>(writes_dst, NE, deg0);
  hist_kernel<<<(NE + 255) / 256, 256, 0, stream>>>(cites_dst, NE, deg1);
  hist_kernel<<<(NE + 255) / 256, 256, 0, stream>>>(wb_dst, NE, deg2);

  const int nbP = (NP + 2047) / 2048;   // 49
  const int nbA = (NA + 2047) / 2048;   // 25
  scan_partial_kernel<<<nbP, 256, 0, stream>>>(deg0, NP, bsum0);
  scan_partial_kernel<<<nbP, 256, 0, stream>>>(deg1, NP, bsum1);
  scan_partial_kernel<<<nbA, 256, 0, stream>>>(deg2, NA, bsum2);
  scan_bsum_kernel<<<1, 64, 0, stream>>>(bsum0, nbP);
  scan_bsum_kernel<<<1, 64, 0, stream>>>(bsum1, nbP);
  scan_bsum_kernel<<<1, 64, 0, stream>>>(bsum2, nbA);
  scan_emit_kernel<<<nbP, 256, 0, stream>>>(deg0, NP, NE, bsum0, off0, cur0);
  scan_emit_kernel<<<nbP, 256, 0, stream>>>(deg1, NP, NE, bsum1, off1, cur1);
  scan_emit_kernel<<<nbA, 256, 0, stream>>>(deg2, NA, NE, bsum2, off2, cur2);

  scatter_kernel<<<(NE + 255) / 256, 256, 0, stream>>>(writes_src, writes_dst, NE, cur0, csr0);
  scatter_kernel<<<(NE + 255) / 256, 256, 0, stream>>>(cites_src, cites_dst, NE, cur1, csr1);
  scatter_kernel<<<(NE + 255) / 256, 256, 0, stream>>>(wb_src, wb_dst, NE, cur2, csr2);

  gemm256<1><<<dim3((NP + 127) / 128, 2), 256, 0, stream>>>(cxp, WinpT, xp, NP, 128, cbinP);
  gemm256<1><<<dim3((NA + 127) / 128, 2), 256, 0, stream>>>(cxa, WinaT, xa, NA, 128, cbinA);

  for (int l = 0; l < 2; ++l) {
    gemm256<0><<<dim3((NA + 127) / 128, 2), 256, 0, stream>>>(xa, linsT + (size_t)(l * 3 + 0) * 65536, hs0, NA, 256, nullptr);
    gemm256<0><<<dim3((NP + 127) / 128, 2), 256, 0, stream>>>(xp, linsT + (size_t)(l * 3 + 1) * 65536, hs1, NP, 256, nullptr);
    gemm256<0><<<dim3((NP + 127) / 128, 2), 256, 0, stream>>>(xp, linsT + (size_t)(l * 3 + 2) * 65536, hs2, NP, 256, nullptr);
    al_kernel<16><<<(NP + 255) / 256, 256, 0, stream>>>(xp, NP, Wp + l * 4096, al_p);
    al_kernel<8><<<(NA + 255) / 256, 256, 0, stream>>>(xa, NA, Wa + l * 2048, al_a);
    if (l == 0) {
      msg_paper_kernel<<<NP / 4, 256, 0, stream>>>(hs0, hs1, al_p, al_a, off0, csr0, off1, csr1,
          cbias + 0 * 256, cbias + 1 * 256, xp, nullptr);
      msg_author_kernel<0><<<NA / 4, 256, 0, stream>>>(hs2, al_p, al_a, off2, csr2,
          cbias + 2 * 256, xa, nullptr);
    } else {
      msg_paper_kernel<<<NP / 4, 256, 0, stream>>>(hs0, hs1, al_p, al_a, off0, csr0, off1, csr1,
          cbias + 3 * 256, cbias + 4 * 256, d_out, flag);
      msg_author_kernel<1><<<NA / 4, 256, 0, stream>>>(hs2, al_p, al_a, off2, csr2,
          cbias + 5 * 256, d_out, flag);
    }
  }
}